// Round 3
// baseline (1152.664 us; speedup 1.0000x reference)
//
#include <hip/hip_runtime.h>

// Problem constants (from reference setup_inputs)
constexpr int kB = 256;
constexpr int kT = 2048;
constexpr int kI = 32;
constexpr int kH = 64;
constexpr int kO = 16;
constexpr int kPadL = 2;
constexpr int kPadR = 3;
constexpr int kTp = kT + kPadL + kPadR;  // 2053
constexpr int kCT = 64;                  // time-chunk staged in LDS (8 KB)
constexpr int kNC = kT / kCT;            // 32 chunks

typedef float v2f __attribute__((ext_vector_type(2)));

// Packed fp32 FMA — same FLOP rate as scalar on CDNA4 (4 cyc/wave) but halves
// instruction count for the off-critical-path x-projection.
__device__ __forceinline__ void pk_fma(v2f& d, v2f a, v2f b) {
  asm("v_pk_fma_f32 %0, %1, %2, %0" : "+v"(d) : "v"(a), "v"(b));
}

// Single-wave workgroup: LDS ordering needs only lgkmcnt, never s_barrier.
__device__ __forceinline__ void lds_fence() {
  asm volatile("s_waitcnt lgkmcnt(0)" ::: "memory");
}

// Register-file broadcast: lane j's value -> SGPR (uniform), no LDS round trip.
__device__ __forceinline__ float bcast(float v, int lane) {
  return __uint_as_float(__builtin_amdgcn_readlane(__float_as_uint(v), lane));
}

// One workgroup (1 wave) per batch element; lane = hidden unit.
// Representation: communicate r_t = 1/(1+e^{2 z_t}); h = 1 - 2r. Affine parts
// folded into pre-scaled weights (see round-2 derivation):
//   2*z_i = [2(b_ih+b_hh+rowsum_i)] + sum_j (2*W_ih[i][j]) x_j
//                                   + sum_j (-4*W_hh[i][j]) r_j
// Step tail: t = __expf(2z); r = rcp(1+t).  h_sum = Tp - 2*sum(r).
// Broadcast of r across lanes is done via v_readlane -> SGPR -> v_fma with
// SGPR operand: the critical path never touches LDS.
__global__ __launch_bounds__(64) void rnn_fused(
    const float* __restrict__ x,
    const float* __restrict__ W_ih,
    const float* __restrict__ W_hh,
    const float* __restrict__ b_ih,
    const float* __restrict__ b_hh,
    const float* __restrict__ W_fc,
    const float* __restrict__ b_fc,
    float* __restrict__ out)
{
  const int b = blockIdx.x;
  const int lane = threadIdx.x;  // hidden unit index

  __shared__ __align__(16) float xbuf[kCT * kI];  // 8 KB staged x chunk
  __shared__ __align__(16) float aggbuf[kH];      // epilogue

  // ---- per-lane weight rows, pre-scaled ----
  float whh[kH];  // -4 * W_hh[lane][j]
  float rowsum = 0.0f;
#pragma unroll
  for (int j = 0; j < kH; j += 4) {
    float4 v = *(const float4*)(W_hh + lane * kH + j);
    rowsum += (v.x + v.y) + (v.z + v.w);
    whh[j + 0] = -4.0f * v.x;
    whh[j + 1] = -4.0f * v.y;
    whh[j + 2] = -4.0f * v.z;
    whh[j + 3] = -4.0f * v.w;
  }
  v2f wi2[kI / 2];  // 2 * W_ih[lane][i]
#pragma unroll
  for (int i = 0; i < kI; i += 4) {
    float4 v = *(const float4*)(W_ih + lane * kI + i);
    wi2[i / 2 + 0] = v2f{2.0f * v.x, 2.0f * v.y};
    wi2[i / 2 + 1] = v2f{2.0f * v.z, 2.0f * v.w};
  }
  const float bias2 = 2.0f * (b_ih[lane] + b_hh[lane] + rowsum);

  float r = 0.5f;     // represents h0 = 0
  float rsum = 0.0f;  // sum of produced r's
  v2f xc0 = v2f{0.0f, 0.0f}, xc1 = v2f{0.0f, 0.0f};  // x-dot for CURRENT step

  // One recurrence step. Critical path: readlane broadcast + 64 SGPR-operand
  // FMAs + exp/rcp tail. Next step's x projection (from xnrow) is independent
  // work the scheduler can sink into the tail's latency.
  auto step = [&](const float4* xnrow) {
    const float rr = r;
    float za = bias2 + xc0.x;
    float zb = xc0.y;
    float zc = xc1.x;
    float zd = xc1.y;
#pragma unroll
    for (int g = 0; g < 4; ++g) {
      float s[16];
#pragma unroll
      for (int j = 0; j < 16; ++j)
        s[j] = bcast(rr, g * 16 + j);
#pragma unroll
      for (int j = 0; j < 16; j += 4) {
        za = fmaf(s[j + 0], whh[g * 16 + j + 0], za);
        zb = fmaf(s[j + 1], whh[g * 16 + j + 1], zb);
        zc = fmaf(s[j + 2], whh[g * 16 + j + 2], zc);
        zd = fmaf(s[j + 3], whh[g * 16 + j + 3], zd);
      }
    }
    // next step's x projection — off the critical path
    v2f xn0 = v2f{0.0f, 0.0f}, xn1 = v2f{0.0f, 0.0f};
    if (xnrow) {
#pragma unroll
      for (int i2 = 0; i2 < 8; ++i2) {
        float4 v = xnrow[i2];
        pk_fma(xn0, wi2[2 * i2 + 0], v2f{v.x, v.y});
        pk_fma(xn1, wi2[2 * i2 + 1], v2f{v.z, v.w});
      }
    }
    float z2 = (za + zb) + (zc + zd);  // = 2*z
    float t = __expf(z2);              // e^{2z}; inf is graceful (r -> 0)
    r = __builtin_amdgcn_rcpf(1.0f + t);
    rsum += r;
    xc0 = xn0;
    xc1 = xn1;
  };

  // ---- prefetch chunk 0 into registers ----
  const float* xb = x + (size_t)b * kT * kI;
  float4 xr[8];
#pragma unroll
  for (int k = 0; k < 8; ++k)
    xr[k] = *(const float4*)(xb + (k * 64 + lane) * 4);

  // left padding: 2 steps with x = 0 (xc starts at 0)
  step(nullptr);
  step(nullptr);

  for (int c = 0; c < kNC; ++c) {
    lds_fence();  // WAR: prior chunk's xbuf reads are complete
#pragma unroll
    for (int k = 0; k < 8; ++k)
      ((float4*)xbuf)[k * 64 + lane] = xr[k];  // compiler waits vmcnt here
    lds_fence();  // staging visible before reads
    if (c + 1 < kNC) {
      const float* src = xb + (size_t)(c + 1) * kCT * kI;
#pragma unroll
      for (int k = 0; k < 8; ++k)
        xr[k] = *(const float4*)(src + (k * 64 + lane) * 4);  // in flight
    }
    // prologue: x contribution of this chunk's step 0
    {
      const float4* row0 = (const float4*)xbuf;
      v2f a0 = v2f{0.0f, 0.0f}, a1 = v2f{0.0f, 0.0f};
#pragma unroll
      for (int i2 = 0; i2 < 8; ++i2) {
        float4 v = row0[i2];
        pk_fma(a0, wi2[2 * i2 + 0], v2f{v.x, v.y});
        pk_fma(a1, wi2[2 * i2 + 1], v2f{v.z, v.w});
      }
      xc0 = a0;
      xc1 = a1;
    }
#pragma unroll 2
    for (int ct = 0; ct < kCT - 1; ++ct)
      step(((const float4*)xbuf) + (ct + 1) * 8);
    step(nullptr);  // ct = 63: next x comes from the next chunk's prologue
  }

  // right padding: 3 steps with x = 0
  step(nullptr);
  step(nullptr);
  step(nullptr);

  // ---- epilogue: mean over Tp, FC (16x64) + ReLU ----
  // hsum = Tp - 2*rsum  ->  aggregated = 1 - 2*rsum/Tp
  aggbuf[lane] = 1.0f - 2.0f * rsum * (1.0f / (float)kTp);
  lds_fence();
  if (lane < kO) {
    float acc = b_fc[lane];
    const float* wf = W_fc + lane * kH;
#pragma unroll
    for (int j = 0; j < kH; ++j)
      acc = fmaf(wf[j], aggbuf[j], acc);
    out[b * kO + lane] = fmaxf(acc, 0.0f);
  }
}

extern "C" void kernel_launch(void* const* d_in, const int* in_sizes, int n_in,
                              void* d_out, int out_size, void* d_ws, size_t ws_size,
                              hipStream_t stream) {
  const float* x    = (const float*)d_in[0];
  const float* W_ih = (const float*)d_in[1];
  const float* W_hh = (const float*)d_in[2];
  const float* b_ih = (const float*)d_in[3];
  const float* b_hh = (const float*)d_in[4];
  const float* W_fc = (const float*)d_in[5];
  const float* b_fc = (const float*)d_in[6];
  float* out = (float*)d_out;

  rnn_fused<<<dim3(kB), dim3(64), 0, stream>>>(x, W_ih, W_hh, b_ih, b_hh,
                                               W_fc, b_fc, out);
}

// Round 4
// 567.518 us; speedup vs baseline: 2.0311x; 2.0311x over previous
//
#include <hip/hip_runtime.h>

// Problem constants (from reference setup_inputs)
constexpr int kB = 256;
constexpr int kT = 2048;
constexpr int kI = 32;
constexpr int kH = 64;
constexpr int kO = 16;
constexpr int kPadL = 2;
constexpr int kPadR = 3;
constexpr int kTp = kT + kPadL + kPadR;  // 2053
constexpr int kCT = 64;                  // timesteps per producer chunk
constexpr int kNC = kT / kCT;            // 32 chunks

constexpr float kS = 1.4426950408889634f;  // log2(e), folded into weights

typedef float    v2f __attribute__((ext_vector_type(2)));
typedef _Float16 v2h __attribute__((ext_vector_type(2)));

// Packed fp32 FMA (same rate as scalar; halves instruction count for producer)
__device__ __forceinline__ void pk_fma(v2f& d, v2f a, v2f b) {
  asm("v_pk_fma_f32 %0, %1, %2, %0" : "+v"(d) : "v"(a), "v"(b));
}

__device__ __forceinline__ v2h as_h2(unsigned u) {
  return __builtin_bit_cast(v2h, u);
}

// f16 dot-2 with f32 accumulate (V_DOT2_F32_F16)
__device__ __forceinline__ float dot2(v2h a, v2h b, float c) {
#if __has_builtin(__builtin_amdgcn_fdot2)
  return __builtin_amdgcn_fdot2(a, b, c, false);
#else
  return fmaf((float)a.x, (float)b.x, fmaf((float)a.y, (float)b.y, c));
#endif
}

__device__ __forceinline__ float exp2_fast(float x) {
#if __has_builtin(__builtin_amdgcn_exp2f)
  return __builtin_amdgcn_exp2f(x);
#else
  return exp2f(x);
#endif
}

// Block = 2 waves per batch element.
//   wave 0 (consumer): the serial recurrence. lane = hidden unit.
//     Communicates r_t = 1/(1+2^{z'_t}) (h = 1-2r) via fp16 LDS broadcast.
//     z'_i = log2e*2*z_i = xin'[t][i] + sum_j (-4*log2e*W_hh[i][j]) r_j
//     Step tail: t = exp2(z'); r = rcp(1+t).  h_sum = Tp - 2*sum(r).
//     NO fence between the r ds_write and the r ds_reads: the DS pipe is
//     in-order within a wave, so the reads observe the write with only
//     pipeline spacing (~130 cyc) instead of a full drain (~250).
//   wave 1 (producer): xin'[t][i] = log2e*2*(b_ih+b_hh+rowsum_i + W_ih[i]·x_t)
//     one chunk (64 steps) ahead, double-buffered in LDS. x rows are read as
//     L1-broadcast global loads (VMEM pipe — keeps the DS pipe for wave 0).
__global__ __launch_bounds__(128) void rnn_fused(
    const float* __restrict__ x,
    const float* __restrict__ W_ih,
    const float* __restrict__ W_hh,
    const float* __restrict__ b_ih,
    const float* __restrict__ b_hh,
    const float* __restrict__ W_fc,
    const float* __restrict__ b_fc,
    float* __restrict__ out)
{
  const int b = blockIdx.x;
  const int lane = threadIdx.x & 63;   // hidden unit index
  const int wave = threadIdx.x >> 6;

  __shared__ __align__(16) float    xinbuf[2][kCT][kH];  // 32 KB double buffer
  __shared__ __align__(16) _Float16 rbuf[kH];            // r broadcast (fp16)
  __shared__ __align__(16) float    aggbuf[kH];          // epilogue

  // Both waves need bias' = 2*kS*(b_ih + b_hh + rowsum(W_hh row lane)).
  float rowsum = 0.0f;
#pragma unroll
  for (int j = 0; j < kH; j += 4) {
    float4 v = *(const float4*)(W_hh + lane * kH + j);
    rowsum += (v.x + v.y) + (v.z + v.w);
  }
  const float bias2 = 2.0f * kS * (b_ih[lane] + b_hh[lane] + rowsum);

  if (wave == 1) {
    // ================= producer =================
    v2f wi2[kI / 2];  // 2*kS*W_ih[lane][i]
#pragma unroll
    for (int i = 0; i < kI; i += 4) {
      float4 v = *(const float4*)(W_ih + lane * kI + i);
      wi2[i / 2 + 0] = v2f{2.0f * kS * v.x, 2.0f * kS * v.y};
      wi2[i / 2 + 1] = v2f{2.0f * kS * v.z, 2.0f * kS * v.w};
    }
    const float* xb = x + (size_t)b * kT * kI;

    auto fill = [&](int c, int buf) {
      const float* src = xb + (size_t)c * kCT * kI;
#pragma unroll 2
      for (int t = 0; t < kCT; ++t) {
        const float4* row = (const float4*)(src + t * kI);  // broadcast loads
        v2f a0 = v2f{0.0f, 0.0f}, a1 = v2f{0.0f, 0.0f};
#pragma unroll
        for (int i2 = 0; i2 < 8; ++i2) {
          float4 v = row[i2];
          pk_fma(a0, wi2[2 * i2 + 0], v2f{v.x, v.y});
          pk_fma(a1, wi2[2 * i2 + 1], v2f{v.z, v.w});
        }
        xinbuf[buf][t][lane] = bias2 + ((a0.x + a0.y) + (a1.x + a1.y));
      }
    };

    fill(0, 0);
    __syncthreads();  // buffer 0 ready
    for (int c = 0; c < kNC; ++c) {
      if (c + 1 < kNC) fill(c + 1, (c + 1) & 1);
      __syncthreads();  // end of chunk c: consumer done with buf c&1
    }
    return;
  }

  // ================= consumer (wave 0) =================
  v2h wh[kH / 2];  // -4*kS*W_hh[lane][j] as fp16 pairs
#pragma unroll
  for (int j = 0; j < kH; j += 2) {
    float w0 = W_hh[lane * kH + j + 0];
    float w1 = W_hh[lane * kH + j + 1];
    wh[j / 2] = v2h{(_Float16)(-4.0f * kS * w0), (_Float16)(-4.0f * kS * w1)};
  }

  float r = 0.5f;     // represents h0 = 0
  float rsum = 0.0f;

  const uint4* rb4 = (const uint4*)rbuf;

  // One recurrence step. xin_p==nullptr (compile-time) => pad step.
  auto step = [&](const float* xin_p) {
    float za = xin_p ? *xin_p : bias2;  // ds_read_b32, independent of rbuf
    rbuf[lane] = (_Float16)r;           // ds_write_b16 — head of the chain
    // In-order DS: these reads observe the write above, no fence needed.
    uint4 q0 = rb4[0], q1 = rb4[1], q2 = rb4[2], q3 = rb4[3];
    uint4 q4 = rb4[4], q5 = rb4[5], q6 = rb4[6], q7 = rb4[7];
    float zb = 0.0f, zc = 0.0f, zd = 0.0f;
    za = dot2(as_h2(q0.x), wh[0], za);
    zb = dot2(as_h2(q0.y), wh[1], zb);
    zc = dot2(as_h2(q0.z), wh[2], zc);
    zd = dot2(as_h2(q0.w), wh[3], zd);
    za = dot2(as_h2(q1.x), wh[4], za);
    zb = dot2(as_h2(q1.y), wh[5], zb);
    zc = dot2(as_h2(q1.z), wh[6], zc);
    zd = dot2(as_h2(q1.w), wh[7], zd);
    za = dot2(as_h2(q2.x), wh[8], za);
    zb = dot2(as_h2(q2.y), wh[9], zb);
    zc = dot2(as_h2(q2.z), wh[10], zc);
    zd = dot2(as_h2(q2.w), wh[11], zd);
    za = dot2(as_h2(q3.x), wh[12], za);
    zb = dot2(as_h2(q3.y), wh[13], zb);
    zc = dot2(as_h2(q3.z), wh[14], zc);
    zd = dot2(as_h2(q3.w), wh[15], zd);
    za = dot2(as_h2(q4.x), wh[16], za);
    zb = dot2(as_h2(q4.y), wh[17], zb);
    zc = dot2(as_h2(q4.z), wh[18], zc);
    zd = dot2(as_h2(q4.w), wh[19], zd);
    za = dot2(as_h2(q5.x), wh[20], za);
    zb = dot2(as_h2(q5.y), wh[21], zb);
    zc = dot2(as_h2(q5.z), wh[22], zc);
    zd = dot2(as_h2(q5.w), wh[23], zd);
    za = dot2(as_h2(q6.x), wh[24], za);
    zb = dot2(as_h2(q6.y), wh[25], zb);
    zc = dot2(as_h2(q6.z), wh[26], zc);
    zd = dot2(as_h2(q6.w), wh[27], zd);
    za = dot2(as_h2(q7.x), wh[28], za);
    zb = dot2(as_h2(q7.y), wh[29], zb);
    zc = dot2(as_h2(q7.z), wh[30], zc);
    zd = dot2(as_h2(q7.w), wh[31], zd);
    float z2 = (za + zb) + (zc + zd);   // = 2*z*log2e
    float t = exp2_fast(z2);            // 2^{z'} = e^{2z}; inf -> r = 0
    r = __builtin_amdgcn_rcpf(1.0f + t);
    rsum += r;
  };

  // left padding: 2 steps with x = 0 (overlaps producer's first fill)
  step(nullptr);
  step(nullptr);
  __syncthreads();  // buffer 0 ready

  for (int c = 0; c < kNC; ++c) {
    const float* xp = &xinbuf[c & 1][0][lane];
#pragma unroll 4
    for (int t = 0; t < kCT; ++t) {
      step(xp);
      xp += kH;
    }
    __syncthreads();  // done with buf c&1
  }

  // right padding: 3 steps with x = 0
  step(nullptr);
  step(nullptr);
  step(nullptr);

  // ---- epilogue: mean over Tp, FC (16x64) + ReLU (single wave: in-order) ----
  aggbuf[lane] = 1.0f - 2.0f * rsum * (1.0f / (float)kTp);
  if (lane < kO) {
    float acc = b_fc[lane];
    const float* wf = W_fc + lane * kH;
#pragma unroll
    for (int j = 0; j < kH; ++j)
      acc = fmaf(wf[j], aggbuf[j], acc);
    out[b * kO + lane] = fmaxf(acc, 0.0f);
  }
}

extern "C" void kernel_launch(void* const* d_in, const int* in_sizes, int n_in,
                              void* d_out, int out_size, void* d_ws, size_t ws_size,
                              hipStream_t stream) {
  const float* x    = (const float*)d_in[0];
  const float* W_ih = (const float*)d_in[1];
  const float* W_hh = (const float*)d_in[2];
  const float* b_ih = (const float*)d_in[3];
  const float* b_hh = (const float*)d_in[4];
  const float* W_fc = (const float*)d_in[5];
  const float* b_fc = (const float*)d_in[6];
  float* out = (float*)d_out;

  rnn_fused<<<dim3(kB), dim3(128), 0, stream>>>(x, W_ih, W_hh, b_ih, b_hh,
                                                W_fc, b_fc, out);
}